// Round 9
// baseline (24.504 us; speedup 1.0000x reference)
//
#include <hip/hip_runtime.h>
#include <math.h>

#define N_IN   2048
#define N_OUT  2048
#define BATCH  64
#define NEG_FILL (-1e9f)
#define TEMP   0.1f
#define INV_TEMP 10.0f
#define NBLK   256       // 2048 rows / 8 rows per block; 1 block/CU
#define ROWS_PB 8
#define MAXH   64        // max entries per half-row segment (mean 7.5)
#define MAXSLOTS 192     // max distinct columns per block (mean ~120)

// ---------------------------------------------------------------------------
// Single fused kernel, one dispatch, no grid sync, no workspace.
// 256 blocks x 1024 threads (16 waves).
//  A : wave wv ballot-compacts mask half-row (row o0+(wv>>1), half wv&1)
//      into LDS CSR segment (idx, ew=exp(w/T)).
//  A2: dedup the block's ~240 entry-columns into ~120 slots via LDS
//      atomicCAS on col2slot[2048] + counter.
//  C : wave wv streams x rows 4wv..4wv+3 (coalesced float4):
//      per-row sum+absmax (replaces the pathological device barrier with
//      cheap redundant recompute; x is L2-resident) AND scatters needed
//      columns into s_xg[slot][b] (slot test = conflict-free int4 LDS read).
//  D : per-wave sparse dot entirely from LDS: lane=batch reads
//      s_xg[sl][lane] (consecutive, conflict-free), gate, exp, accumulate.
//      Halves merge in LDS, log, staged 32B-contiguous write.
// ---------------------------------------------------------------------------
__global__ __launch_bounds__(1024) void fused_kernel(const float* __restrict__ x,
                                                     const float* __restrict__ w,
                                                     const float* __restrict__ mask,
                                                     float* __restrict__ out) {
    const int tid  = threadIdx.x;
    const int wv   = tid >> 6;          // 0..15
    const int lane = tid & 63;
    const int blk  = blockIdx.x;
    const int o0   = blk * ROWS_PB;

    __shared__ int   s_idx[16][MAXH];
    __shared__ float s_ew [16][MAXH];
    __shared__ int   s_cnt[16];
    __shared__ int   s_col2slot[N_IN];          // -1 unused, else slot id
    __shared__ int   s_nslots;
    __shared__ float s_xg[MAXSLOTS][BATCH];     // gathered x columns
    __shared__ float s_rsum[BATCH];
    __shared__ float s_ramax[BATCH];
    __shared__ float s_acc[16][BATCH];
    __shared__ float s_res[ROWS_PB][BATCH + 1];

    // ---------------- init ---------------------------------------------------
    s_col2slot[tid]        = -1;
    s_col2slot[tid + 1024] = -1;
    if (tid == 0) s_nslots = 0;

    // ---------------- phase A: compaction of this wave's half-row -----------
    const int row = o0 + (wv >> 1);
    const int hh  = wv & 1;
    const float4* mrow = reinterpret_cast<const float4*>(mask + (size_t)row * N_IN) + hh * 256;
    const float*  wrow = w + (size_t)row * N_IN;
    const int     ih0  = hh * 1024;
    const unsigned long long below = (1ull << lane) - 1ull;
    int cnt = 0;
#pragma unroll
    for (int r = 0; r < 4; ++r) {
        const float4 mv = mrow[r * 64 + lane];
        const int base  = ih0 + (r * 64 + lane) * 4;
        {
            const bool f = (mv.x != 0.f);
            const unsigned long long bal = __ballot(f);
            if (f) { int p = cnt + __popcll(bal & below);
                     if (p < MAXH) { s_idx[wv][p] = base + 0;
                                     s_ew[wv][p]  = __expf(wrow[base + 0] * INV_TEMP); } }
            cnt += __popcll(bal);
        }
        {
            const bool f = (mv.y != 0.f);
            const unsigned long long bal = __ballot(f);
            if (f) { int p = cnt + __popcll(bal & below);
                     if (p < MAXH) { s_idx[wv][p] = base + 1;
                                     s_ew[wv][p]  = __expf(wrow[base + 1] * INV_TEMP); } }
            cnt += __popcll(bal);
        }
        {
            const bool f = (mv.z != 0.f);
            const unsigned long long bal = __ballot(f);
            if (f) { int p = cnt + __popcll(bal & below);
                     if (p < MAXH) { s_idx[wv][p] = base + 2;
                                     s_ew[wv][p]  = __expf(wrow[base + 2] * INV_TEMP); } }
            cnt += __popcll(bal);
        }
        {
            const bool f = (mv.w != 0.f);
            const unsigned long long bal = __ballot(f);
            if (f) { int p = cnt + __popcll(bal & below);
                     if (p < MAXH) { s_idx[wv][p] = base + 3;
                                     s_ew[wv][p]  = __expf(wrow[base + 3] * INV_TEMP); } }
            cnt += __popcll(bal);
        }
    }
    cnt = min(cnt, MAXH);
    if (lane == 0) s_cnt[wv] = cnt;
    __syncthreads();   // col2slot init + all compactions visible

    // ---------------- A2: dedup slot assignment -----------------------------
    if (lane < cnt) {
        const int c = s_idx[wv][lane];
        if (atomicCAS(&s_col2slot[c], -1, -2) == -1) {
            const int sl = atomicAdd(&s_nslots, 1);
            s_col2slot[c] = sl;                 // plain store; visible after sync
        }
    }
    __syncthreads();

    // ---------------- phase C: stream x — stats + scatter -------------------
    const int4* slot4 = reinterpret_cast<const int4*>(s_col2slot);
#pragma unroll
    for (int r = 0; r < 4; ++r) {
        const int b = wv * 4 + r;
        const float4* xr = reinterpret_cast<const float4*>(x + (size_t)b * N_IN);
        float sum = 0.f, amax = 0.f;
#pragma unroll
        for (int it = 0; it < 8; ++it) {
            const int   c4 = it * 64 + lane;
            const float4 v  = xr[c4];
            const int4  sl4 = slot4[c4];        // conflict-free b128 LDS read
            sum += v.x + v.y + v.z + v.w;
            amax = fmaxf(amax, fmaxf(fmaxf(fabsf(v.x), fabsf(v.y)),
                                     fmaxf(fabsf(v.z), fabsf(v.w))));
            if (sl4.x >= 0 && sl4.x < MAXSLOTS) s_xg[sl4.x][b] = v.x;
            if (sl4.y >= 0 && sl4.y < MAXSLOTS) s_xg[sl4.y][b] = v.y;
            if (sl4.z >= 0 && sl4.z < MAXSLOTS) s_xg[sl4.z][b] = v.z;
            if (sl4.w >= 0 && sl4.w < MAXSLOTS) s_xg[sl4.w][b] = v.w;
        }
        for (int off = 32; off; off >>= 1) {
            sum += __shfl_xor(sum, off);
            amax = fmaxf(amax, __shfl_xor(amax, off));
        }
        if (lane == 0) { s_rsum[b] = sum; s_ramax[b] = amax; }
    }
    __syncthreads();

    // ---------------- stats finalize (wave-redundant) -----------------------
    float mx = s_ramax[lane];
    for (int off = 32; off; off >>= 1) mx = fmaxf(mx, __shfl_xor(mx, off));
    const float dinv = 1.0f / (mx + 1e-6f);
    const float cons = s_rsum[lane] * dinv * (1.0f / (float)N_IN);   // lane = batch

    // ---------------- phase D: sparse dot from LDS (lane = batch) -----------
    const float* xrow = x + (size_t)lane * N_IN;   // fallback only (slot overflow)
    float acc = 0.f;
    int k = 0;
    for (; k + 2 <= cnt; k += 2) {
        const int   c0 = s_idx[wv][k + 0], c1 = s_idx[wv][k + 1];
        const float e0 = s_ew[wv][k + 0],  e1 = s_ew[wv][k + 1];
        const int   sl0 = s_col2slot[c0],  sl1 = s_col2slot[c1];
        const float x0 = (sl0 < MAXSLOTS) ? s_xg[sl0][lane] : xrow[c0];
        const float x1 = (sl1 < MAXSLOTS) ? s_xg[sl1][lane] : xrow[c1];
        const float v0 = x0 * dinv;
        const float v1 = x1 * dinv;
        const float g0 = (fabsf(v0 - cons) < 1.0f) ? v0 : 0.f;
        const float g1 = (fabsf(v1 - cons) < 1.0f) ? v1 : 0.f;
        acc += e0 * __expf(g0 * INV_TEMP);
        acc += e1 * __expf(g1 * INV_TEMP);
    }
    if (k < cnt) {
        const int   c_ = s_idx[wv][k];
        const float e_ = s_ew[wv][k];
        const int   sl = s_col2slot[c_];
        const float xv = (sl < MAXSLOTS) ? s_xg[sl][lane] : xrow[c_];
        const float v  = xv * dinv;
        const float g  = (fabsf(v - cons) < 1.0f) ? v : 0.f;
        acc += e_ * __expf(g * INV_TEMP);
    }

    s_acc[wv][lane] = acc;
    __syncthreads();
    if (hh == 0) {
        const float total = s_acc[wv][lane] + s_acc[wv + 1][lane];
        const int   tcnt  = s_cnt[wv] + s_cnt[wv + 1];
        const float res   = (tcnt > 0) ? TEMP * logf(total)
                                       : NEG_FILL + TEMP * logf((float)N_IN);
        s_res[wv >> 1][lane] = res;
    }
    __syncthreads();
    if (tid < 512) {
        const int b = tid >> 3, c = tid & 7;   // 32B contiguous per batch
        out[(size_t)b * N_OUT + o0 + c] = s_res[c][b];
    }
}

extern "C" void kernel_launch(void* const* d_in, const int* in_sizes, int n_in,
                              void* d_out, int out_size, void* d_ws, size_t ws_size,
                              hipStream_t stream) {
    const float* x    = (const float*)d_in[0];
    const float* wgt  = (const float*)d_in[1];
    const float* mask = (const float*)d_in[2];
    float* out = (float*)d_out;
    (void)d_ws; (void)ws_size;

    fused_kernel<<<NBLK, 1024, 0, stream>>>(x, wgt, mask, out);
}

// Round 10
// 17.384 us; speedup vs baseline: 1.4096x; 1.4096x over previous
//
#include <hip/hip_runtime.h>
#include <math.h>

#define N_IN   2048
#define N_OUT  2048
#define BATCH  64
#define NEG_FILL (-1e9f)
#define TEMP   0.1f
#define INV_TEMP 10.0f
#define MAXH   64        // max nz per half-row (mean 7.5)

// ws layout (floats): [0..63] row sums, [64..127] row absmax, [128..] xT[2048][64]
#define WS_XT_OFF 128

// ---------------------------------------------------------------------------
// Kernel 1: tiny prep. 96 blocks x 256 threads, reads only x (512 KB).
//   blocks 0..63  : per-row sum + absmax of x row b
//   blocks 64..95 : transpose a 64-wide i-tile of x into xT[i][b]
// ---------------------------------------------------------------------------
__global__ __launch_bounds__(256) void prep_kernel(const float* __restrict__ x,
                                                   float* __restrict__ ws) {
    const int tid = threadIdx.x;

    if (blockIdx.x < 64) {
        const int b = blockIdx.x;
        const float4* row = reinterpret_cast<const float4*>(x + (size_t)b * N_IN);
        float sum = 0.f, amax = 0.f;
#pragma unroll
        for (int it = 0; it < 2; ++it) {
            float4 v = row[tid + it * 256];
            sum += v.x + v.y + v.z + v.w;
            amax = fmaxf(amax, fmaxf(fmaxf(fabsf(v.x), fabsf(v.y)),
                                     fmaxf(fabsf(v.z), fabsf(v.w))));
        }
        for (int off = 32; off; off >>= 1) {
            sum += __shfl_xor(sum, off);
            amax = fmaxf(amax, __shfl_xor(amax, off));
        }
        __shared__ float s_sum[4], s_amax[4];
        const int wid = tid >> 6;
        if ((tid & 63) == 0) { s_sum[wid] = sum; s_amax[wid] = amax; }
        __syncthreads();
        if (tid == 0) {
            ws[b]         = (s_sum[0] + s_sum[1]) + (s_sum[2] + s_sum[3]);
            ws[BATCH + b] = fmaxf(fmaxf(s_amax[0], s_amax[1]),
                                  fmaxf(s_amax[2], s_amax[3]));
        }
    } else {
        __shared__ float t[64][65];
        const int i0 = (blockIdx.x - 64) * 64;
        const int il = tid & 63;
        const int q  = tid >> 6;
        float* xT = ws + WS_XT_OFF;
#pragma unroll
        for (int r = 0; r < 16; ++r) {
            const int b = r * 4 + q;
            t[il][b] = x[(size_t)b * N_IN + i0 + il];
        }
        __syncthreads();
#pragma unroll
        for (int r = 0; r < 16; ++r) {
            const int i_l = r * 4 + q;
            xT[(size_t)(i0 + i_l) * 64 + il] = t[i_l][il];
        }
    }
}

// ---------------------------------------------------------------------------
// Kernel 2: compaction + sparse dot fused (mask read exactly once, here).
// 512 blocks x 512 threads (8 waves) = 4 output rows per block, 2 waves/row.
//  - wave wv: ballot-compact half-row (row o0+(wv>>1), half wv&1) into
//    wave-private LDS CSR (idx, ew=exp(w/T)); then immediately dot against
//    xT (lane = batch, coalesced 256B column reads), acc per half.
//  - halves merge by addition in LDS; T*log; staged 16B-contiguous write.
// ---------------------------------------------------------------------------
__global__ __launch_bounds__(512) void spdot_kernel(const float* __restrict__ w,
                                                    const float* __restrict__ mask,
                                                    const float* __restrict__ ws,
                                                    float* __restrict__ out) {
    const int tid  = threadIdx.x;
    const int wv   = tid >> 6;          // 0..7
    const int lane = tid & 63;
    const int o0   = blockIdx.x * 4;
    const int row  = o0 + (wv >> 1);
    const int hh   = wv & 1;

    __shared__ int   s_idx[8][MAXH];
    __shared__ float s_ew [8][MAXH];
    __shared__ int   s_cnt[8];
    __shared__ float s_acc[8][BATCH];
    __shared__ float s_res[4][BATCH + 1];

    // ---- stats (produced by prep_kernel): dinv global, cons per batch ----
    const float sum_l = ws[lane];
    float mx = ws[BATCH + lane];
    for (int off = 32; off; off >>= 1) mx = fmaxf(mx, __shfl_xor(mx, off));
    const float dinv = 1.0f / (mx + 1e-6f);
    const float cons = sum_l * dinv * (1.0f / (float)N_IN);   // lane = batch

    // ---- ballot compaction of this wave's half-row ----
    const float4* mrow = reinterpret_cast<const float4*>(mask + (size_t)row * N_IN) + hh * 256;
    const float*  wrow = w + (size_t)row * N_IN;
    const int     ih0  = hh * 1024;
    const unsigned long long below = (1ull << lane) - 1ull;
    int cnt = 0;
#pragma unroll
    for (int r = 0; r < 4; ++r) {
        const float4 mv = mrow[r * 64 + lane];
        const int base  = ih0 + (r * 64 + lane) * 4;
        {
            const bool f = (mv.x != 0.f);
            const unsigned long long bal = __ballot(f);
            if (f) { int p = cnt + __popcll(bal & below);
                     if (p < MAXH) { s_idx[wv][p] = base + 0;
                                     s_ew[wv][p]  = __expf(wrow[base + 0] * INV_TEMP); } }
            cnt += __popcll(bal);
        }
        {
            const bool f = (mv.y != 0.f);
            const unsigned long long bal = __ballot(f);
            if (f) { int p = cnt + __popcll(bal & below);
                     if (p < MAXH) { s_idx[wv][p] = base + 1;
                                     s_ew[wv][p]  = __expf(wrow[base + 1] * INV_TEMP); } }
            cnt += __popcll(bal);
        }
        {
            const bool f = (mv.z != 0.f);
            const unsigned long long bal = __ballot(f);
            if (f) { int p = cnt + __popcll(bal & below);
                     if (p < MAXH) { s_idx[wv][p] = base + 2;
                                     s_ew[wv][p]  = __expf(wrow[base + 2] * INV_TEMP); } }
            cnt += __popcll(bal);
        }
        {
            const bool f = (mv.w != 0.f);
            const unsigned long long bal = __ballot(f);
            if (f) { int p = cnt + __popcll(bal & below);
                     if (p < MAXH) { s_idx[wv][p] = base + 3;
                                     s_ew[wv][p]  = __expf(wrow[base + 3] * INV_TEMP); } }
            cnt += __popcll(bal);
        }
    }
    cnt = min(cnt, MAXH);
    if (lane == 0) s_cnt[wv] = cnt;

    // ---- dot over this wave's entries; lane = batch; xT columns L2-hot ----
    const float* xT = ws + WS_XT_OFF;
    float acc = 0.f;
    int k = 0;
    for (; k + 2 <= cnt; k += 2) {
        const int   i0_ = s_idx[wv][k + 0], i1_ = s_idx[wv][k + 1];
        const float e0  = s_ew[wv][k + 0],  e1  = s_ew[wv][k + 1];
        const float v0  = xT[(size_t)i0_ * 64 + lane] * dinv;
        const float v1  = xT[(size_t)i1_ * 64 + lane] * dinv;
        const float g0  = (fabsf(v0 - cons) < 1.0f) ? v0 : 0.f;
        const float g1  = (fabsf(v1 - cons) < 1.0f) ? v1 : 0.f;
        acc += e0 * __expf(g0 * INV_TEMP);
        acc += e1 * __expf(g1 * INV_TEMP);
    }
    if (k < cnt) {
        const int   i_ = s_idx[wv][k];
        const float e_ = s_ew[wv][k];
        const float v  = xT[(size_t)i_ * 64 + lane] * dinv;
        const float g  = (fabsf(v - cons) < 1.0f) ? v : 0.f;
        acc += e_ * __expf(g * INV_TEMP);
    }

    // ---- merge halves (sum), log, staged 16B write ----
    s_acc[wv][lane] = acc;
    __syncthreads();
    if (hh == 0) {
        const float total = s_acc[wv][lane] + s_acc[wv + 1][lane];
        const int   tcnt  = s_cnt[wv] + s_cnt[wv + 1];
        const float res   = (tcnt > 0) ? TEMP * logf(total)
                                       : NEG_FILL + TEMP * logf((float)N_IN);
        s_res[wv >> 1][lane] = res;
    }
    __syncthreads();
    if (tid < 256) {
        const int b = tid >> 2, c = tid & 3;   // 16B contiguous per batch
        out[(size_t)b * N_OUT + o0 + c] = s_res[c][b];
    }
}

extern "C" void kernel_launch(void* const* d_in, const int* in_sizes, int n_in,
                              void* d_out, int out_size, void* d_ws, size_t ws_size,
                              hipStream_t stream) {
    const float* x    = (const float*)d_in[0];
    const float* wgt  = (const float*)d_in[1];
    const float* mask = (const float*)d_in[2];
    float* out = (float*)d_out;
    float* ws  = (float*)d_ws;   // 128 + 2048*64 floats

    prep_kernel<<<96, 256, 0, stream>>>(x, ws);
    spdot_kernel<<<N_OUT / 4, 512, 0, stream>>>(wgt, mask, ws, out);
}